// Round 7
// baseline (231.977 us; speedup 1.0000x reference)
//
#include <hip/hip_runtime.h>
#include <hip/hip_bf16.h>
#include <hip/hip_cooperative_groups.h>
#include <stdint.h>

namespace cg = cooperative_groups;

#define BB 2
#define TT 4096
#define CC 512
#define HH 8
#define MEM 256

typedef unsigned short u16;
typedef __bf16 bf16x8 __attribute__((ext_vector_type(8)));
typedef float floatx4 __attribute__((ext_vector_type(4)));

__device__ inline u16 f2bf(float f) {  // RNE
  uint32_t u = __float_as_uint(f);
  uint32_t r = (u + 0x7fffu + ((u >> 16) & 1u)) >> 16;
  return (u16)r;
}
__device__ inline u16 f2bf_r(float f) {  // round-half-up (2 ops), p>=0 only
  return (u16)((__float_as_uint(f) + 0x8000u) >> 16);
}

__device__ inline void gld16(const u16* g, u16* lds) {
  __builtin_amdgcn_global_load_lds(
      (const __attribute__((address_space(1))) uint32_t*)g,
      (__attribute__((address_space(3))) uint32_t*)lds, 16, 0, 0);
}

#define BARM() asm volatile("" ::: "memory")

// =========================== phase bodies ==================================
// R1-R4 measurement rounds: per-dispatch overhead ~9us x 5 dispatches ~= 45us
// of the 126us total (kernels only ~40us, harness fill 44.5us fixed). This
// round fuses all 4 kernels into ONE cooperative launch (grid 256 x 512thr,
// 1 block/CU) with 3 grid.sync()s. Phase bodies are the R6 kernels verbatim.

// ---------------- phase 0: fp32 -> bf16 convert (grid-stride) --------------
__device__ __forceinline__ void cvt_body(int gtid, int stride,
                                         const float* __restrict__ x,
                                         const float* __restrict__ wa,
                                         const float* __restrict__ wp,
                                         u16* __restrict__ xb,
                                         u16* __restrict__ wab,
                                         u16* __restrict__ wpb) {
  for (int i = gtid; i < 1310720; i += stride) {
    const float* s; u16* d; int off;
    if (i < 1048576) { s = x; d = xb; off = i; }
    else if (i < 1245184) { s = wa; d = wab; off = i - 1048576; }
    else { s = wp; d = wpb; off = i - 1245184; }
    float4 v = *reinterpret_cast<const float4*>(s + (size_t)off * 4);
    ushort4 o;
    o.x = f2bf(v.x); o.y = f2bf(v.y); o.z = f2bf(v.z); o.w = f2bf(v.w);
    *reinterpret_cast<ushort4*>(d + (size_t)off * 4) = o;
  }
}

// ---------------- phase 1: 256x192 4-phase QKV GEMM (R6 verbatim) ----------
__device__ __forceinline__ void stage_hA(const u16* __restrict__ G, u16* lds, int K,
                                         int gr0, int koff, int half, int wv, int lane) {
#pragma unroll
  for (int j = 0; j < 2; j++) {
    int lrow = (j * 8 + wv) * 8 + (lane >> 3);
    int row = (lrow & 63) + ((lrow >> 6) << 7) + (half << 6);
    int blk = (lane & 7) ^ (row & 7);
    gld16(G + (size_t)(gr0 + row) * K + koff + blk * 8,
          lds + (size_t)row * 64 + (lane & 7) * 8);
  }
}
__device__ __forceinline__ void stage_hB(const u16* __restrict__ G, u16* lds, int K,
                                         int gr0, int koff, int half, int wv, int lane) {
  if (half == 0) {
#pragma unroll
    for (int j = 0; j < 2; j++) {
      int lrow = (j * 8 + wv) * 8 + (lane >> 3);
      int row = (lrow & 31) + (lrow >> 5) * 48;
      int blk = (lane & 7) ^ (row & 7);
      gld16(G + (size_t)(gr0 + row) * K + koff + blk * 8,
            lds + (size_t)row * 64 + (lane & 7) * 8);
    }
  } else {
    int lrow = wv * 8 + (lane >> 3);
    int row = 32 + (lrow & 15) + (lrow >> 4) * 48;
    int blk = (lane & 7) ^ (row & 7);
    gld16(G + (size_t)(gr0 + row) * K + koff + blk * 8,
          lds + (size_t)row * 64 + (lane & 7) * 8);
  }
}

#define PHASE(MQ, NQ, NF, STAGE, WAITV)                                        \
  {                                                                            \
    bf16x8 af[4][2], bfv[NF][2];                                               \
    _Pragma("unroll") for (int fm = 0; fm < 4; fm++) {                         \
      int row = wm * 128 + MQ * 64 + fm * 16 + l16;                            \
      const u16* p = Ad + (size_t)row * 64;                                    \
      af[fm][0] = *(const bf16x8*)(p + ((quad ^ (row & 7)) << 3));             \
      af[fm][1] = *(const bf16x8*)(p + (((4 + quad) ^ (row & 7)) << 3));       \
    }                                                                          \
    _Pragma("unroll") for (int fn = 0; fn < NF; fn++) {                        \
      int row = wn * 48 + NQ * 32 + fn * 16 + l16;                             \
      const u16* p = Bd + (size_t)row * 64;                                    \
      bfv[fn][0] = *(const bf16x8*)(p + ((quad ^ (row & 7)) << 3));            \
      bfv[fn][1] = *(const bf16x8*)(p + (((4 + quad) ^ (row & 7)) << 3));      \
    }                                                                          \
    STAGE;                                                                     \
    BARM();                                                                    \
    __builtin_amdgcn_s_barrier();                                              \
    asm volatile("s_waitcnt lgkmcnt(0)" ::: "memory");                         \
    __builtin_amdgcn_sched_barrier(0);                                         \
    __builtin_amdgcn_s_setprio(1);                                             \
    _Pragma("unroll") for (int fm = 0; fm < 4; fm++)                           \
      _Pragma("unroll") for (int fn = 0; fn < NF; fn++) {                      \
        acc[MQ * 4 + fm][NQ * 2 + fn] =                                        \
            __builtin_amdgcn_mfma_f32_16x16x32_bf16(                           \
                af[fm][0], bfv[fn][0], acc[MQ * 4 + fm][NQ * 2 + fn], 0, 0, 0);\
        acc[MQ * 4 + fm][NQ * 2 + fn] =                                        \
            __builtin_amdgcn_mfma_f32_16x16x32_bf16(                           \
                af[fm][1], bfv[fn][1], acc[MQ * 4 + fm][NQ * 2 + fn], 0, 0, 0);\
      }                                                                        \
    __builtin_amdgcn_s_setprio(0);                                             \
    WAITV;                                                                     \
    BARM();                                                                    \
    __builtin_amdgcn_s_barrier();                                              \
    BARM();                                                                    \
  }

__device__ __forceinline__ void gemm_body(const u16* __restrict__ A,
                                          const u16* __restrict__ Bw,
                                          u16* __restrict__ C,
                                          int M, int N, int K,
                                          u16* sm, int tid, int bx) {
  u16* As0 = sm;            // 256*64
  u16* As1 = sm + 16384;
  u16* Bs0 = sm + 32768;    // 192*64
  u16* Bs1 = sm + 45056;
  const int lane = tid & 63, wv = tid >> 6;
  const int quad = lane >> 4, l16 = lane & 15;
  const int wm = wv >> 2, wn = wv & 3;

  const int nbx = N / 192;
  const int nwg = (M >> 8) * nbx;
  int wg = bx;
  if ((nwg & 7) == 0) wg = (wg & 7) * (nwg >> 3) + (wg >> 3);
  const int m0 = (wg / nbx) << 8, n0 = (wg % nbx) * 192;

  const int nK = K >> 6;
  floatx4 acc[8][3] = {};

  stage_hA(A, As0, K, m0, 0, 0, wv, lane);
  stage_hA(A, As0, K, m0, 0, 1, wv, lane);
  stage_hB(Bw, Bs0, K, n0, 0, 0, wv, lane);
  stage_hB(Bw, Bs0, K, n0, 0, 1, wv, lane);
  if (nK > 1) {
    stage_hA(A, As1, K, m0, 64, 0, wv, lane);
    stage_hB(Bw, Bs1, K, n0, 64, 0, wv, lane);
    asm volatile("s_waitcnt vmcnt(4)" ::: "memory");
  } else {
    asm volatile("s_waitcnt vmcnt(0)" ::: "memory");
  }
  BARM();
  __builtin_amdgcn_s_barrier();
  BARM();

  for (int t = 0; t < nK; ++t) {
    const int d = t & 1;
    u16* Ad = d ? As1 : As0; u16* Bd = d ? Bs1 : Bs0;
    u16* An = d ? As0 : As1; u16* Bn = d ? Bs0 : Bs1;
    const int k1 = (t + 1) << 6, k2 = (t + 2) << 6;

    PHASE(0, 0, 2, { if (t + 1 < nK) stage_hA(A, An, K, m0, k1, 1, wv, lane); }, {})
    PHASE(0, 1, 1, { if (t + 1 < nK) stage_hB(Bw, Bn, K, n0, k1, 1, wv, lane); }, {})
    PHASE(1, 0, 2, { if (t + 2 < nK) stage_hA(A, Ad, K, m0, k2, 0, wv, lane); }, {})
    PHASE(1, 1, 1, { if (t + 2 < nK) stage_hB(Bw, Bd, K, n0, k2, 0, wv, lane); },
          { if (t + 2 < nK) asm volatile("s_waitcnt vmcnt(4)" ::: "memory");
            else            asm volatile("s_waitcnt vmcnt(0)" ::: "memory"); })
  }

#pragma unroll
  for (int mi = 0; mi < 8; mi++) {
    int row = m0 + wm * 128 + mi * 16 + quad * 4;
#pragma unroll
    for (int ni = 0; ni < 3; ni++) {
      int col = n0 + wn * 48 + ni * 16 + l16;
#pragma unroll
      for (int r = 0; r < 4; r++)
        C[(size_t)(row + r) * N + col] = f2bf(acc[mi][ni][r]);
    }
  }
}

// ---------------- phase 2: windowed flash attention (R6 verbatim) ----------
// base: 26112 u16 region = Qs[8192] Ks[4096] Vt[4608] Ps[4*2304]
__device__ __forceinline__ void attn_body(const u16* __restrict__ qkv,
                                          u16* __restrict__ y,
                                          int q0, int h, int b, int t,
                                          u16* base) {
  u16* Qs = base;
  u16* Ks = base + 8192;
  u16* Vt = base + 12288;
  u16* Ps0 = base + 16896;
  const int w = t >> 6, lane = t & 63, quad = lane >> 4, l16 = lane & 15;
  u16* Psw = Ps0 + w * 2304;

  const size_t baseQ = ((size_t)(b * TT + q0)) * 1536 + h * 64;
#pragma unroll
  for (int j = 0; j < 4; j++) {
    int c = t + j * 256, row = c >> 3, blk = (c & 7) ^ (row & 7);
    gld16(qkv + baseQ + (size_t)row * 1536 + blk * 8, Qs + (size_t)c * 8);
  }
  __syncthreads();
  bf16x8 qf[2][2];
#pragma unroll
  for (int mi = 0; mi < 2; mi++) {
    int row = w * 32 + mi * 16 + l16;
    qf[mi][0] = *reinterpret_cast<const bf16x8*>(&Qs[row * 64 + (quad ^ (l16 & 7)) * 8]);
    qf[mi][1] = *reinterpret_cast<const bf16x8*>(&Qs[row * 64 + ((quad + 4) ^ (l16 & 7)) * 8]);
#pragma unroll
    for (int e = 0; e < 8; e++) {
      qf[mi][0][e] = qf[mi][0][e] * (__bf16)0.125f;
      qf[mi][1][e] = qf[mi][1][e] * (__bf16)0.125f;
    }
  }

  floatx4 acc_o[2][4] = {};
  float l_acc[2][4] = {{0.f, 0.f, 0.f, 0.f}, {0.f, 0.f, 0.f, 0.f}};

  const int s_min = (q0 >= 256) ? 0 : ((256 - q0) >> 6);
  const int key_v = t >> 3, dc_v = t & 7;
  const int key_v1 = (t + 256) >> 3, dc_v1 = t & 7;

  uint4 vp0, vp1;
  {
    size_t baseV = ((size_t)(b * TT + (q0 - 256 + s_min * 64))) * 1536 + 1024 + h * 64;
    vp0 = *reinterpret_cast<const uint4*>(qkv + baseV + (size_t)key_v * 1536 + dc_v * 8);
    vp1 = *reinterpret_cast<const uint4*>(qkv + baseV + (size_t)key_v1 * 1536 + dc_v1 * 8);
  }

  for (int s = s_min; s < 6; ++s) {
    const int k0 = q0 - 256 + s * 64;
    const size_t baseK = ((size_t)(b * TT + k0)) * 1536 + 512 + h * 64;
    {
      int c = t, row = c >> 3, blk = (c & 7) ^ (row & 7);
      gld16(qkv + baseK + (size_t)row * 1536 + blk * 8, Ks + (size_t)c * 8);
      c = t + 256; row = c >> 3; blk = (c & 7) ^ (row & 7);
      gld16(qkv + baseK + (size_t)row * 1536 + blk * 8, Ks + (size_t)c * 8);
    }
    {
      u16 tmp[8];
      *reinterpret_cast<uint4*>(tmp) = vp0;
      int col = key_v ^ (dc_v * 8);
#pragma unroll
      for (int e = 0; e < 8; e++) Vt[(dc_v * 8 + e) * 72 + col] = tmp[e];
      *reinterpret_cast<uint4*>(tmp) = vp1;
      col = key_v1 ^ (dc_v1 * 8);
#pragma unroll
      for (int e = 0; e < 8; e++) Vt[(dc_v1 * 8 + e) * 72 + col] = tmp[e];
    }
    if (s < 5) {
      size_t baseV = ((size_t)(b * TT + k0 + 64)) * 1536 + 1024 + h * 64;
      vp0 = *reinterpret_cast<const uint4*>(qkv + baseV + (size_t)key_v * 1536 + dc_v * 8);
      vp1 = *reinterpret_cast<const uint4*>(qkv + baseV + (size_t)key_v1 * 1536 + dc_v1 * 8);
    }
    __syncthreads();

    int mode = 0;
    if (s == 0) mode = (w < 2) ? 1 : 3;
    else if (s == 1) mode = (w < 2) ? 0 : 1;
    else if (s == 4) mode = (w < 2) ? 2 : 0;
    else if (s == 5) mode = (w < 2) ? 3 : 2;

    if (mode != 3) {
      bf16x8 bfr[4][2];
#pragma unroll
      for (int nt = 0; nt < 4; nt++) {
        int krow = nt * 16 + l16;
        bfr[nt][0] = *reinterpret_cast<const bf16x8*>(&Ks[krow * 64 + (quad ^ (l16 & 7)) * 8]);
        bfr[nt][1] = *reinterpret_cast<const bf16x8*>(&Ks[krow * 64 + ((quad + 4) ^ (l16 & 7)) * 8]);
      }
      floatx4 sc[2][4] = {};
#pragma unroll
      for (int mi = 0; mi < 2; mi++)
#pragma unroll
        for (int nt = 0; nt < 4; nt++) {
          sc[mi][nt] = __builtin_amdgcn_mfma_f32_16x16x32_bf16(qf[mi][0], bfr[nt][0], sc[mi][nt], 0, 0, 0);
          sc[mi][nt] = __builtin_amdgcn_mfma_f32_16x16x32_bf16(qf[mi][1], bfr[nt][1], sc[mi][nt], 0, 0, 0);
        }
      const int hqb = (w & 1) * 32 + quad * 4;
      if (mode == 1) {
#pragma unroll
        for (int mi = 0; mi < 2; mi++)
#pragma unroll
          for (int nt = 0; nt < 4; nt++)
#pragma unroll
            for (int r = 0; r < 4; r++)
              if (hqb + mi * 16 + r > nt * 16 + l16) sc[mi][nt][r] = -1e30f;
      } else if (mode == 2) {
#pragma unroll
        for (int mi = 0; mi < 2; mi++)
#pragma unroll
          for (int nt = 0; nt < 4; nt++)
#pragma unroll
            for (int r = 0; r < 4; r++)
              if (hqb + mi * 16 + r < nt * 16 + l16) sc[mi][nt][r] = -1e30f;
      }
#pragma unroll
      for (int mi = 0; mi < 2; mi++)
#pragma unroll
        for (int nt = 0; nt < 4; nt++)
#pragma unroll
          for (int r = 0; r < 4; r++) {
            float p = __expf(sc[mi][nt][r] - 4.0f);
            l_acc[mi][r] += p;
            Psw[(mi * 16 + quad * 4 + r) * 72 + nt * 16 + l16] = f2bf_r(p);
          }
#pragma unroll
      for (int mi = 0; mi < 2; mi++)
#pragma unroll
        for (int ki = 0; ki < 2; ki++) {
          bf16x8 pf = *reinterpret_cast<const bf16x8*>(
              &Psw[(mi * 16 + l16) * 72 + ki * 32 + quad * 8]);
#pragma unroll
          for (int nt = 0; nt < 4; nt++) {
            int d = nt * 16 + l16;
            bf16x8 vf = *reinterpret_cast<const bf16x8*>(
                &Vt[d * 72 + ((ki * 32 + quad * 8) ^ (d & 56))]);
            acc_o[mi][nt] = __builtin_amdgcn_mfma_f32_16x16x32_bf16(pf, vf, acc_o[mi][nt], 0, 0, 0);
          }
        }
    }
    __syncthreads();
  }
#pragma unroll
  for (int mi = 0; mi < 2; mi++)
#pragma unroll
    for (int r = 0; r < 4; r++) {
      float l = l_acc[mi][r];
      l += __shfl_xor(l, 1);
      l += __shfl_xor(l, 2);
      l += __shfl_xor(l, 4);
      l += __shfl_xor(l, 8);
      float inv = 1.f / l;
      int row = q0 + w * 32 + mi * 16 + quad * 4 + r;
      size_t base2 = (size_t)(b * TT + row) * 512 + h * 64;
#pragma unroll
      for (int nt = 0; nt < 4; nt++)
        y[base2 + nt * 16 + l16] = f2bf(acc_o[mi][nt][r] * inv);
    }
}

// ---------------- phase 3: output proj 128x64 tile (R6 verbatim) -----------
// sm: 6144 u16 = As[128*32] + Bs[64*32]
__device__ __forceinline__ void proj_body(const u16* __restrict__ A,
                                          const u16* __restrict__ Bw,
                                          float* __restrict__ C,
                                          int m0, int n0, int t, u16* sm) {
  u16* As = sm;
  u16* Bs = sm + 4096;
  const int w = t >> 6, lane = t & 63, quad = lane >> 4, l16 = lane & 15;
  const int K = 512, N = 512;
  floatx4 acc[2][4] = {};
  for (int kb = 0; kb < 16; ++kb) {
    const int kof = kb * 32;
    {
      int c = t;
      gld16(A + (size_t)(m0 + (c >> 2)) * K + kof + (c & 3) * 8, As + (size_t)c * 8);
      c = t + 256;
      gld16(A + (size_t)(m0 + (c >> 2)) * K + kof + (c & 3) * 8, As + (size_t)c * 8);
      c = t;
      gld16(Bw + (size_t)(n0 + (c >> 2)) * K + kof + (c & 3) * 8, Bs + (size_t)c * 8);
    }
    __syncthreads();
    bf16x8 af[2], bfr[4];
#pragma unroll
    for (int i = 0; i < 2; i++)
      af[i] = *reinterpret_cast<const bf16x8*>(&As[(w * 32 + i * 16 + l16) * 32 + quad * 8]);
#pragma unroll
    for (int i = 0; i < 4; i++)
      bfr[i] = *reinterpret_cast<const bf16x8*>(&Bs[(i * 16 + l16) * 32 + quad * 8]);
#pragma unroll
    for (int mi = 0; mi < 2; mi++)
#pragma unroll
      for (int ni = 0; ni < 4; ni++)
        acc[mi][ni] = __builtin_amdgcn_mfma_f32_16x16x32_bf16(af[mi], bfr[ni], acc[mi][ni], 0, 0, 0);
    __syncthreads();
  }
#pragma unroll
  for (int mi = 0; mi < 2; mi++) {
    int row = m0 + w * 32 + mi * 16 + quad * 4;
#pragma unroll
    for (int ni = 0; ni < 4; ni++) {
      int col = n0 + ni * 16 + l16;
#pragma unroll
      for (int r = 0; r < 4; r++)
        C[(size_t)(row + r) * N + col] = acc[mi][ni][r];
    }
  }
}

// =========================== mega kernel ===================================
// grid 256 x 512thr, cooperative. LDS 57344 u16 = 112 KiB (1 block/CU).
// phase2: two (b,h) attn instances per block (halves, disjoint 26112-u16 LDS
// regions, identical barrier counts since both share q0). phase3: two
// adjacent 128x64 proj tiles per block.
__global__ __launch_bounds__(512, 2) void mega(const float* __restrict__ x,
                                               const float* __restrict__ wa,
                                               const float* __restrict__ wp,
                                               float* __restrict__ out,
                                               u16* __restrict__ xb,
                                               u16* __restrict__ wab,
                                               u16* __restrict__ wpb,
                                               u16* __restrict__ qkv,
                                               u16* __restrict__ yb) {
  __shared__ __align__(16) u16 sm[57344];
  const int tid = threadIdx.x;
  cg::grid_group grid = cg::this_grid();

  // phase 0: convert
  cvt_body(blockIdx.x * 512 + tid, 256 * 512, x, wa, wp, xb, wab, wpb);
  grid.sync();

  // phase 1: QKV GEMM (exactly 256 blocks' worth)
  gemm_body(xb, wab, qkv, 8192, 1536, 512, sm, tid, blockIdx.x);
  grid.sync();

  // phase 2: attention — 2 instances per block
  {
    const int half = tid >> 8, t = tid & 255;
    const int qt = blockIdx.x >> 3, pr = blockIdx.x & 7;
    const int c = pr * 2 + half;
    const int b = c >> 3, h = c & 7;
    attn_body(qkv, yb, qt * 128, h, b, t, sm + half * 26112);
  }
  grid.sync();

  // phase 3: output projection — 2 tiles per block
  {
    const int half = tid >> 8, t = tid & 255;
    const int m0 = (blockIdx.x >> 2) * 128;
    const int n0 = (blockIdx.x & 3) * 128 + half * 64;
    proj_body(yb, wpb, out, m0, n0, t, sm + half * 6144);
  }
}

// ===================== standalone fallback kernels =========================
__global__ __launch_bounds__(256) void cvt_all(const float* __restrict__ x,
                                               const float* __restrict__ wa,
                                               const float* __restrict__ wp,
                                               u16* __restrict__ xb,
                                               u16* __restrict__ wab,
                                               u16* __restrict__ wpb) {
  cvt_body(blockIdx.x * 256 + threadIdx.x, gridDim.x * 256, x, wa, wp, xb, wab, wpb);
}

__global__ __launch_bounds__(512, 2) void gemm256(const u16* __restrict__ A,
                                                  const u16* __restrict__ Bw,
                                                  u16* __restrict__ C,
                                                  int M, int N, int K) {
  __shared__ __align__(16) u16 sm[57344];
  gemm_body(A, Bw, C, M, N, K, sm, threadIdx.x, blockIdx.x);
}

__global__ __launch_bounds__(256, 2) void attn_win(const u16* __restrict__ qkv,
                                                   u16* __restrict__ y) {
  __shared__ __align__(16) u16 sm[26112];
  attn_body(qkv, y, blockIdx.x * 128, blockIdx.y, blockIdx.z, threadIdx.x, sm);
}

__global__ __launch_bounds__(256) void gemm_bt_n64(const u16* __restrict__ A,
                                                   const u16* __restrict__ Bw,
                                                   float* __restrict__ C) {
  __shared__ __align__(16) u16 sm[6144];
  proj_body(A, Bw, C, blockIdx.x * 128, blockIdx.y * 64, threadIdx.x, sm);
}

extern "C" void kernel_launch(void* const* d_in, const int* in_sizes, int n_in,
                              void* d_out, int out_size, void* d_ws, size_t ws_size,
                              hipStream_t stream) {
  const float* x = (const float*)d_in[0];       // [2,4096,512]
  const float* w_attn = (const float*)d_in[1];  // [1536,512]
  const float* w_proj = (const float*)d_in[2];  // [512,512]
  float* out = (float*)d_out;                   // [2,4096,512] fp32

  u16* xb = (u16*)d_ws;
  u16* wab = xb + (size_t)8192 * 512;
  u16* wpb = wab + (size_t)1536 * 512;
  u16* qkv = wpb + (size_t)512 * 512;
  u16* yb = qkv + (size_t)8192 * 1536;

  void* args[] = {(void*)&x, (void*)&w_attn, (void*)&w_proj, (void*)&out,
                  (void*)&xb, (void*)&wab, (void*)&wpb, (void*)&qkv, (void*)&yb};
  hipError_t rc = hipLaunchCooperativeKernel((const void*)mega, dim3(256), dim3(512),
                                             args, 0, stream);
  if (rc != hipSuccess) {
    // fallback: proven 4-dispatch path (R6)
    cvt_all<<<5120, 256, 0, stream>>>(x, w_attn, w_proj, xb, wab, wpb);
    gemm256<<<256, 512, 0, stream>>>(xb, wab, qkv, 8192, 1536, 512);
    attn_win<<<dim3(TT / 128, HH, BB), 256, 0, stream>>>(qkv, yb);
    gemm_bt_n64<<<dim3(64, 8), 256, 0, stream>>>(yb, wpb, out);
  }
}